// Round 7
// baseline (287.202 us; speedup 1.0000x reference)
//
#include <hip/hip_runtime.h>
#include <cstddef>

#define B_      4
#define N_      1024
#define DIM_    512
#define H_      8
#define D_      64
#define INNER_  512
#define TRIPLE_ 1536
#define KK_     716        // int(1024 * 0.7)
#define SCALE_  0.125f     // 64^-0.5

typedef short bf16x8 __attribute__((ext_vector_type(8)));
typedef float f32x4  __attribute__((ext_vector_type(4)));
typedef unsigned short ushort_t;
typedef ushort_t us8 __attribute__((ext_vector_type(8)));

__device__ __forceinline__ unsigned short bf16_rne(float f) {
    unsigned u = __float_as_uint(f);
    return (unsigned short)((u + 0x7FFFu + ((u >> 16) & 1u)) >> 16);
}
__device__ __forceinline__ float bf16_f(unsigned short s) {
    return __uint_as_float((unsigned)s << 16);
}
// order-preserving float->uint key (descending float == descending uint)
__device__ __forceinline__ unsigned f2key(float f) {
    unsigned u = __float_as_uint(f);
    return u ^ ((u & 0x80000000u) ? 0xFFFFFFFFu : 0x80000000u);
}
__device__ __forceinline__ float key2f(unsigned k) {
    unsigned u = (k & 0x80000000u) ? (k ^ 0x80000000u) : ~k;
    return __uint_as_float(u);
}
// load 8 contiguous f32, emit hi/lo bf16 fragments
__device__ __forceinline__ void split8(const float* __restrict__ src,
                                       bf16x8& h8, bf16x8& l8) {
    float4 a = *(const float4*)src;
    float4 b = *(const float4*)(src + 4);
    float v[8] = {a.x, a.y, a.z, a.w, b.x, b.y, b.z, b.w};
#pragma unroll
    for (int i = 0; i < 8; ++i) {
        ushort_t hb = bf16_rne(v[i]);
        h8[i] = (short)hb;
        l8[i] = (short)bf16_rne(v[i] - bf16_f(hb));
    }
}

// ---------------------------------------------------------------------------
// Fused weight transpose+split: blocks [0,48) -> w_qkv, [48,64) -> w_out.
// W[K][Nn] f32 -> Th[Nn][K], Tl[Nn][K] bf16. K = 512 for both.
// ---------------------------------------------------------------------------
__global__ __launch_bounds__(256) void conv_wT2(const float* __restrict__ Wq,
                                                const float* __restrict__ Wo,
                                                ushort_t* __restrict__ WqTh,
                                                ushort_t* __restrict__ WqTl,
                                                ushort_t* __restrict__ WoTh,
                                                ushort_t* __restrict__ WoTl) {
    __shared__ float tile[32][33];
    const bool isQ = blockIdx.x < 48;
    const int  nb  = (isQ ? blockIdx.x : blockIdx.x - 48) * 32;
    const int  kb  = blockIdx.y * 32;
    const int  Nn  = isQ ? TRIPLE_ : DIM_;
    const float* W = isQ ? Wq : Wo;
    ushort_t* Th   = isQ ? WqTh : WoTh;
    ushort_t* Tl   = isQ ? WqTl : WoTl;
    const int tx = threadIdx.x & 31, ty = threadIdx.x >> 5;   // ty 0..7
    for (int yy = ty; yy < 32; yy += 8)
        tile[yy][tx] = W[(size_t)(kb + yy) * Nn + nb + tx];
    __syncthreads();
    for (int yy = ty; yy < 32; yy += 8) {
        float v = tile[tx][yy];
        ushort_t hb = bf16_rne(v);
        size_t idx = (size_t)(nb + yy) * DIM_ + kb + tx;
        Th[idx] = hb;
        Tl[idx] = bf16_rne(v - bf16_f(hb));
    }
}

// ---------------------------------------------------------------------------
// Split-bf16 MFMA GEMM core (bf16 A inputs): wave = 32x64, WG = 4 waves.
// ---------------------------------------------------------------------------
#define GEMM_CORE(K_DIM, AH, AL, BH, BL)                                     \
    const int t = threadIdx.x, w = t >> 6, l = t & 63;                       \
    const int ln = l & 15, quad = l >> 4;                                    \
    const int n0 = blockIdx.y * 64;                                          \
    const int m0 = blockIdx.x * 128 + w * 32;                                \
    f32x4 acc[2][4] = {};                                                    \
    {                                                                        \
        const size_t arow0 = (size_t)(m0 + ln) * (K_DIM);                    \
        const size_t arow1 = (size_t)(m0 + 16 + ln) * (K_DIM);               \
        for (int k0 = 0; k0 < (K_DIM); k0 += 32) {                           \
            const int ko = k0 + quad * 8;                                    \
            bf16x8 ah0 = *(const bf16x8*)&AH[arow0 + ko];                    \
            bf16x8 al0 = *(const bf16x8*)&AL[arow0 + ko];                    \
            bf16x8 ah1 = *(const bf16x8*)&AH[arow1 + ko];                    \
            bf16x8 al1 = *(const bf16x8*)&AL[arow1 + ko];                    \
            _Pragma("unroll")                                                \
            for (int j = 0; j < 4; ++j) {                                    \
                const size_t brow = (size_t)(n0 + j * 16 + ln) * (K_DIM) + ko; \
                bf16x8 bh = *(const bf16x8*)&BH[brow];                       \
                bf16x8 bl = *(const bf16x8*)&BL[brow];                       \
                acc[0][j] = __builtin_amdgcn_mfma_f32_16x16x32_bf16(ah0, bh, acc[0][j], 0, 0, 0); \
                acc[0][j] = __builtin_amdgcn_mfma_f32_16x16x32_bf16(al0, bh, acc[0][j], 0, 0, 0); \
                acc[0][j] = __builtin_amdgcn_mfma_f32_16x16x32_bf16(ah0, bl, acc[0][j], 0, 0, 0); \
                acc[1][j] = __builtin_amdgcn_mfma_f32_16x16x32_bf16(ah1, bh, acc[1][j], 0, 0, 0); \
                acc[1][j] = __builtin_amdgcn_mfma_f32_16x16x32_bf16(al1, bh, acc[1][j], 0, 0, 0); \
                acc[1][j] = __builtin_amdgcn_mfma_f32_16x16x32_bf16(ah1, bl, acc[1][j], 0, 0, 0); \
            }                                                                \
        }                                                                    \
    }

// qkv GEMM: reads x fp32 directly, splits A frags in-register.
// Q/K and V epilogues both stage the 32x64 wave tile in LDS so every global
// write is a full-width us8 chunk (128B token rows / 64B Vt line halves).
__global__ __launch_bounds__(256) void gemm_qkv_mfma(
    const float* __restrict__ X,
    const ushort_t* __restrict__ Wh, const ushort_t* __restrict__ Wl,
    ushort_t* __restrict__ Qh, ushort_t* __restrict__ Ql,
    ushort_t* __restrict__ Kh, ushort_t* __restrict__ Kl,
    ushort_t* __restrict__ Vt) {
    __shared__ ushort_t stile[4][4608];   // 36 KB, per-wave scratch
    const int t = threadIdx.x, w = t >> 6, l = t & 63;
    const int ln = l & 15, quad = l >> 4;
    const int n0 = blockIdx.y * 64;
    const int m0 = blockIdx.x * 128 + w * 32;
    f32x4 acc[2][4] = {};
    {
        const size_t xrow0 = (size_t)(m0 + ln) * DIM_;
        const size_t xrow1 = (size_t)(m0 + 16 + ln) * DIM_;
        for (int k0 = 0; k0 < DIM_; k0 += 32) {
            const int ko = k0 + quad * 8;
            bf16x8 ah0, al0, ah1, al1;
            split8(&X[xrow0 + ko], ah0, al0);
            split8(&X[xrow1 + ko], ah1, al1);
#pragma unroll
            for (int j = 0; j < 4; ++j) {
                const size_t brow = (size_t)(n0 + j * 16 + ln) * DIM_ + ko;
                bf16x8 bh = *(const bf16x8*)&Wh[brow];
                bf16x8 bl = *(const bf16x8*)&Wl[brow];
                acc[0][j] = __builtin_amdgcn_mfma_f32_16x16x32_bf16(ah0, bh, acc[0][j], 0, 0, 0);
                acc[0][j] = __builtin_amdgcn_mfma_f32_16x16x32_bf16(al0, bh, acc[0][j], 0, 0, 0);
                acc[0][j] = __builtin_amdgcn_mfma_f32_16x16x32_bf16(ah0, bl, acc[0][j], 0, 0, 0);
                acc[1][j] = __builtin_amdgcn_mfma_f32_16x16x32_bf16(ah1, bh, acc[1][j], 0, 0, 0);
                acc[1][j] = __builtin_amdgcn_mfma_f32_16x16x32_bf16(al1, bh, acc[1][j], 0, 0, 0);
                acc[1][j] = __builtin_amdgcn_mfma_f32_16x16x32_bf16(ah1, bl, acc[1][j], 0, 0, 0);
            }
        }
    }
    const int sec = n0 >> 9;           // block-uniform
    const int h   = (n0 >> 6) & 7;
    ushort_t* tw  = stile[w];
    const int b = m0 >> 10, nnb = m0 & 1023;
    if (sec < 2) {
        ushort_t* Hp = sec ? Kh : Qh;
        ushort_t* Lp = sec ? Kl : Ql;
        // stage: hi tile rows at tok*72, lo tile at 2304 + tok*72
#pragma unroll
        for (int i = 0; i < 2; ++i)
#pragma unroll
            for (int j = 0; j < 4; ++j)
#pragma unroll
                for (int g = 0; g < 4; ++g) {
                    const float v = acc[i][j][g];
                    const ushort_t hb = bf16_rne(v);
                    const ushort_t lb = bf16_rne(v - bf16_f(hb));
                    const int tok = i * 16 + quad * 4 + g;
                    const int d   = j * 16 + ln;
                    tw[tok * 72 + d]        = hb;
                    tw[2304 + tok * 72 + d] = lb;
                }
        __syncthreads();
        const size_t rowbase = ((size_t)(b * 8 + h) * 1024 + nnb) * 64;
        const int dd = (l & 7) * 8;
#pragma unroll
        for (int s = 0; s < 4; ++s) {
            const int tl = s * 8 + (l >> 3);
            const size_t off = rowbase + (size_t)tl * 64 + dd;
            *(us8*)&Hp[off] = *(const us8*)&tw[tl * 72 + dd];
            *(us8*)&Lp[off] = *(const us8*)&tw[2304 + tl * 72 + dd];
        }
    } else {
        // V: tile [d(64)][tok stride 40]
#pragma unroll
        for (int i = 0; i < 2; ++i)
#pragma unroll
            for (int j = 0; j < 4; ++j)
#pragma unroll
                for (int g = 0; g < 4; ++g)
                    tw[(j * 16 + ln) * 40 + i * 16 + quad * 4 + g] = bf16_rne(acc[i][j][g]);
        __syncthreads();
        const size_t vbase = (size_t)(b * 8 + h) * 65536 + nnb;
#pragma unroll
        for (int p = 0; p < 2; ++p) {
            const int d = (p << 5) + (l >> 1);
            const int c = (l & 1) << 4;
            ushort_t* dst = &Vt[vbase + (size_t)d * 1024 + c];
            *(us8*)dst       = *(const us8*)&tw[d * 40 + c];
            *(us8*)(dst + 8) = *(const us8*)&tw[d * 40 + c + 8];
        }
    }
}

// out-proj: fp32 C + bias
__global__ __launch_bounds__(256) void gemm_out_mfma(
    const ushort_t* __restrict__ Ah, const ushort_t* __restrict__ Al,
    const ushort_t* __restrict__ Wh, const ushort_t* __restrict__ Wl,
    const float* __restrict__ bias, float* __restrict__ C) {
    GEMM_CORE(INNER_, Ah, Al, Wh, Wl)
#pragma unroll
    for (int i = 0; i < 2; ++i)
#pragma unroll
        for (int j = 0; j < 4; ++j) {
            const int col = n0 + j * 16 + ln;
            const float bb = bias[col];
#pragma unroll
            for (int g = 0; g < 4; ++g) {
                const int token = m0 + i * 16 + quad * 4 + g;
                C[(size_t)token * DIM_ + col] = acc[i][j][g] + bb;
            }
        }
}

// softmax over one row's keys + normalized bf16 P store (phase-3 layout)
__device__ __forceinline__ void softmax_store(const unsigned* key, unsigned res,
                                              int r, int l, ushort_t* sP) {
    const float thr = key2f(res);
    float pv[16];
    float lsum = 0.f;
#pragma unroll
    for (int m = 0; m < 16; ++m) {
        float p = (key[m] >= res) ? __expf(key2f(key[m]) - thr) : 0.f;
        pv[m] = p;
        lsum += p;
    }
#pragma unroll
    for (int off = 32; off; off >>= 1) lsum += __shfl_xor(lsum, off, 64);
    const float inv = 1.f / lsum;
#pragma unroll
    for (int m = 0; m < 4; ++m) {
        const int g = ((l >> 1) + (m << 5)) ^ (r & 7);
        ushort4 pk = make_ushort4(bf16_rne(pv[(m << 2) + 0] * inv),
                                  bf16_rne(pv[(m << 2) + 1] * inv),
                                  bf16_rne(pv[(m << 2) + 2] * inv),
                                  bf16_rne(pv[(m << 2) + 3] * inv));
        *(ushort4*)&sP[(r << 11) + (g << 3) + ((l & 1) << 2)] = pk;
    }
}

// ---------------------------------------------------------------------------
// MFMA kNN attention. WG = 512 thr (8 waves) = (b,h, 16 q-rows).
// bh = wg & 31 => all 64 blocks of a head share one XCD (K/V L2-resident).
// Phase 2: each wave's TWO rows run ONE interleaved binary search (2
// independent dependency chains per wave -> 2x ILP vs r6's sequential rows).
// ---------------------------------------------------------------------------
__global__ __launch_bounds__(512) void attn_mfma(const ushort_t* __restrict__ Qh,
                                                 const ushort_t* __restrict__ Ql,
                                                 const ushort_t* __restrict__ Kh,
                                                 const ushort_t* __restrict__ Kl,
                                                 const ushort_t* __restrict__ Vt,
                                                 ushort_t* __restrict__ Oh,
                                                 ushort_t* __restrict__ Ol) {
    __shared__ float sdots[16 * 1024];        // 64 KB
    __shared__ float spartial[4][16][17];     // 4.25 KB j-split merge buffer

    const int t    = threadIdx.x;
    const int w    = t >> 6;        // wave 0..7
    const int l    = t & 63;
    const int ln   = l & 15;
    const int quad = l >> 4;
    const int wg   = blockIdx.x;
    const int bh   = wg & 31;       // XCD-local heads
    const int i0   = (wg >> 5) << 4;

    const size_t bhoff = (size_t)bh << 16;

    // ---- Q fragments (same for all waves)
    const ushort_t* qp  = Qh + bhoff + (size_t)(i0 + ln) * 64 + (quad << 3);
    const ushort_t* qlp = Ql + bhoff + (size_t)(i0 + ln) * 64 + (quad << 3);
    bf16x8 qh0 = *(const bf16x8*)qp;
    bf16x8 qh1 = *(const bf16x8*)(qp + 32);
    bf16x8 ql0 = *(const bf16x8*)qlp;
    bf16x8 ql1 = *(const bf16x8*)(qlp + 32);

    // ---- Phase 1: dots. wave w covers j in [w*128, w*128+128)
    for (int tt = 0; tt < 8; ++tt) {
        const int j0 = ((w << 3) + tt) << 4;
        const ushort_t* kp  = Kh + bhoff + (size_t)(j0 + ln) * 64 + (quad << 3);
        const ushort_t* klp = Kl + bhoff + (size_t)(j0 + ln) * 64 + (quad << 3);
        bf16x8 kh0 = *(const bf16x8*)kp;
        bf16x8 kh1 = *(const bf16x8*)(kp + 32);
        bf16x8 kl0 = *(const bf16x8*)klp;
        bf16x8 kl1 = *(const bf16x8*)(klp + 32);
        f32x4 acc = {0.f, 0.f, 0.f, 0.f};
        acc = __builtin_amdgcn_mfma_f32_16x16x32_bf16(qh0, kh0, acc, 0, 0, 0);
        acc = __builtin_amdgcn_mfma_f32_16x16x32_bf16(qh1, kh1, acc, 0, 0, 0);
        acc = __builtin_amdgcn_mfma_f32_16x16x32_bf16(qh0, kl0, acc, 0, 0, 0);
        acc = __builtin_amdgcn_mfma_f32_16x16x32_bf16(qh1, kl1, acc, 0, 0, 0);
        acc = __builtin_amdgcn_mfma_f32_16x16x32_bf16(ql0, kh0, acc, 0, 0, 0);
        acc = __builtin_amdgcn_mfma_f32_16x16x32_bf16(ql1, kh1, acc, 0, 0, 0);
#pragma unroll
        for (int g = 0; g < 4; ++g) {
            const int row = (quad << 2) + g;
            sdots[(row << 10) + ((j0 + ln) ^ ((row & 7) << 2))] = acc[g] * SCALE_;
        }
    }
    __syncthreads();

    // ---- Phase 2: fused 2-row top-k + softmax + in-place bf16 P
    ushort_t* sP = (ushort_t*)sdots;
    {
        const int r0 = w << 1, r1 = r0 | 1;
        const int swz0 = (r0 & 7) << 2, swz1 = (r1 & 7) << 2;
        const float* s0 = &sdots[r0 << 10];
        const float* s1 = &sdots[r1 << 10];
        // lane l holds keys for j = 4l + 256m + i  (m=0..3, i=0..3)
        unsigned key0[16], key1[16];
#pragma unroll
        for (int m = 0; m < 4; ++m) {
            f32x4 kv0 = *(const f32x4*)&s0[((l << 2) + (m << 8)) ^ swz0];
            f32x4 kv1 = *(const f32x4*)&s1[((l << 2) + (m << 8)) ^ swz1];
#pragma unroll
            for (int i = 0; i < 4; ++i) {
                key0[(m << 2) + i] = f2key(kv0[i]);
                key1[(m << 2) + i] = f2key(kv1[i]);
            }
        }
        unsigned res0 = 0u, res1 = 0u;
        int done = 0;
        for (int bit = 31; bit >= 0; --bit) {
            const unsigned t0v = res0 | (1u << bit);
            const unsigned t1v = res1 | (1u << bit);
            int p0 = 0, p1 = 0, p2 = 0, p3 = 0;
            int q0 = 0, q1 = 0, q2 = 0, q3 = 0;
#pragma unroll
            for (int m = 0; m < 4; ++m) {
                p0 += key0[(m << 2) + 0] >= t0v;
                p1 += key0[(m << 2) + 1] >= t0v;
                p2 += key0[(m << 2) + 2] >= t0v;
                p3 += key0[(m << 2) + 3] >= t0v;
                q0 += key1[(m << 2) + 0] >= t1v;
                q1 += key1[(m << 2) + 1] >= t1v;
                q2 += key1[(m << 2) + 2] >= t1v;
                q3 += key1[(m << 2) + 3] >= t1v;
            }
            const int lc0 = (p0 + p1) + (p2 + p3);
            const int lc1 = (q0 + q1) + (q2 + q3);
            const int c0 = __popcll(__ballot(lc0 & 1)) + (__popcll(__ballot(lc0 & 2)) << 1) +
                           (__popcll(__ballot(lc0 & 4)) << 2) + (__popcll(__ballot(lc0 & 8)) << 3) +
                           (__popcll(__ballot(lc0 & 16)) << 4);
            const int c1 = __popcll(__ballot(lc1 & 1)) + (__popcll(__ballot(lc1 & 2)) << 1) +
                           (__popcll(__ballot(lc1 & 4)) << 2) + (__popcll(__ballot(lc1 & 8)) << 3) +
                           (__popcll(__ballot(lc1 & 16)) << 4);
            if (!(done & 1) && c0 >= KK_) { res0 = t0v; if (c0 == KK_) done |= 1; }
            if (!(done & 2) && c1 >= KK_) { res1 = t1v; if (c1 == KK_) done |= 2; }
            if (done == 3) break;   // wave-uniform
        }
        softmax_store(key0, res0, r0, l, sP);
        softmax_store(key1, res1, r1, l, sP);
    }
    __syncthreads();

    // ---- Phase 3: O = P @ V.  wave w: d-block (w&3), j-half (w&4 ? hi : lo)
    const int dblk  = w & 3;
    const int jbase = (w & 4) << 7;   // 0 or 512
    f32x4 oacc = {0.f, 0.f, 0.f, 0.f};
    const ushort_t* vp =
        Vt + bhoff + (size_t)((dblk << 4) + ln) * 1024 + (quad << 3) + jbase;
    const int prow = ln << 11;
    const int rsw  = ln & 7;
    for (int j0 = 0; j0 < 512; j0 += 32) {
        const int g = ((jbase + j0) >> 3) + quad;
        bf16x8 af = *(const bf16x8*)&sP[prow + ((g ^ rsw) << 3)];
        bf16x8 bv = *(const bf16x8*)(vp + j0);
        oacc = __builtin_amdgcn_mfma_f32_16x16x32_bf16(af, bv, oacc, 0, 0, 0);
    }
    if (w & 4) {
#pragma unroll
        for (int g = 0; g < 4; ++g)
            spartial[dblk][(quad << 2) + g][ln] = oacc[g];
    }
    __syncthreads();
    if (!(w & 4)) {
        const int b = bh >> 3, h = bh & 7;
        const size_t obase =
            ((size_t)(b << 10) + i0 + (quad << 2)) * 512 + (h << 6) + (dblk << 4) + ln;
#pragma unroll
        for (int g = 0; g < 4; ++g) {
            const float v = oacc[g] + spartial[dblk][(quad << 2) + g][ln];
            ushort_t hb = bf16_rne(v);
            Oh[obase + (size_t)g * 512] = hb;
            Ol[obase + (size_t)g * 512] = bf16_rne(v - bf16_f(hb));
        }
    }
}

extern "C" void kernel_launch(void* const* d_in, const int* in_sizes, int n_in,
                              void* d_out, int out_size, void* d_ws, size_t ws_size,
                              hipStream_t stream) {
    const float* x     = (const float*)d_in[0];
    const float* w_qkv = (const float*)d_in[1];
    const float* w_out = (const float*)d_in[2];
    const float* b_out = (const float*)d_in[3];
    float*       out   = (float*)d_out;

    const size_t ON  = (size_t)4096 * 512;
    const size_t WQT = (size_t)1536 * 512;
    const size_t WOT = (size_t)512 * 512;
    const size_t QK  = (size_t)32 * 1024 * 64;

    ushort_t* p    = (ushort_t*)d_ws;
    ushort_t* Oh   = p;            p += ON;
    ushort_t* Ol   = p;            p += ON;
    ushort_t* WqTh = p;            p += WQT;
    ushort_t* WqTl = p;            p += WQT;
    ushort_t* WoTh = p;            p += WOT;
    ushort_t* WoTl = p;            p += WOT;
    ushort_t* Qh   = p;            p += QK;
    ushort_t* Ql   = p;            p += QK;
    ushort_t* Kh   = p;            p += QK;
    ushort_t* Kl   = p;            p += QK;
    ushort_t* Vt   = p;            p += QK;   // total exactly 32 MiB

    conv_wT2<<<dim3(64, 16), 256, 0, stream>>>(w_qkv, w_out, WqTh, WqTl, WoTh, WoTl);

    // blockIdx.x = m-block so A tiles are XCD-local
    gemm_qkv_mfma<<<dim3(4096 / 128, TRIPLE_ / 64), 256, 0, stream>>>(
        x, WqTh, WqTl, Qh, Ql, Kh, Kl, Vt);

    attn_mfma<<<dim3(B_ * H_ * (N_ / 16)), 512, 0, stream>>>(Qh, Ql, Kh, Kl, Vt, Oh, Ol);

    gemm_out_mfma<<<dim3(4096 / 128, DIM_ / 64), 256, 0, stream>>>(
        Oh, Ol, WoTh, WoTl, b_out, out);
}